// Round 13
// baseline (785.251 us; speedup 1.0000x reference)
//
#include <hip/hip_runtime.h>
#include <hip/hip_bf16.h>

typedef short bf16x8 __attribute__((ext_vector_type(8)));
typedef float f32x4  __attribute__((ext_vector_type(4)));

#define NH    16
#define NG    4
#define HD    96
#define DM    1536
#define BB    2
#define NSEQ  2048
#define QKVD  2304
#define MROWS (BB * NSEQ)   // 4096
// grid dims fixed by setup_inputs: 8 x 16 x 16 (t,h,w), N = 2048

__device__ __forceinline__ short bf16_bits(float v)
{
    __hip_bfloat16 h = __float2bfloat16(v);
    return *reinterpret_cast<short*>(&h);
}

__device__ __forceinline__ float bf16_val(short v)
{
    __hip_bfloat16 h = *reinterpret_cast<__hip_bfloat16*>(&v);
    return __bfloat162float(h);
}

// ---- staging: 16 contiguous elements -> 16 bf16 shorts in LDS -------------
__device__ __forceinline__ void stage16(short* dst, const float* src)
{
    float f[16];
    *(float4*)(f + 0)  = *(const float4*)(src + 0);
    *(float4*)(f + 4)  = *(const float4*)(src + 4);
    *(float4*)(f + 8)  = *(const float4*)(src + 8);
    *(float4*)(f + 12) = *(const float4*)(src + 12);
    bf16x8 v0, v1;
    #pragma unroll
    for (int j = 0; j < 8; ++j) { v0[j] = bf16_bits(f[j]); v1[j] = bf16_bits(f[8 + j]); }
    *(bf16x8*)dst = v0;
    *(bf16x8*)(dst + 8) = v1;
}
__device__ __forceinline__ void stage16(short* dst, const __hip_bfloat16* src)
{
    *(bf16x8*)dst       = *(const bf16x8*)src;
    *(bf16x8*)(dst + 8) = *(const bf16x8*)(src + 8);
}

__device__ __forceinline__ void store_c(__hip_bfloat16* p, float v)
{
    *p = __float2bfloat16(v);
}
__device__ __forceinline__ void store_c(float* p, float v) { *p = v; }

// ---- async global->LDS, 16B per lane (m97 pattern) ------------------------
__device__ __forceinline__ void gload_lds16(const short* g, short* lds)
{
    __builtin_amdgcn_global_load_lds(
        (const __attribute__((address_space(1))) unsigned int*)g,
        (__attribute__((address_space(3))) unsigned int*)lds,
        16, 0, 0);
}

// ---------------------------------------------------------------------------
// fp32 -> bf16 bulk convert (one pass): x (786432 u8), w_qkv (442368 u8),
// w_o (294912 u8). 8 elems / thread, fully coalesced.
// ---------------------------------------------------------------------------
__global__ __launch_bounds__(256) void cvt3_bf16(
    const float* __restrict__ x,  short* __restrict__ xb,
    const float* __restrict__ wq, short* __restrict__ wqb,
    const float* __restrict__ wo, short* __restrict__ wob)
{
    const int i = blockIdx.x * 256 + threadIdx.x;
    const float* s; short* d; int off;
    if (i < 786432)       { s = x;  d = xb;  off = i; }
    else if (i < 1228800) { s = wq; d = wqb; off = i - 786432; }
    else                  { s = wo; d = wob; off = i - 1228800; }
    float f[8];
    *(float4*)(f + 0) = *(const float4*)(s + (size_t)off * 8);
    *(float4*)(f + 4) = *(const float4*)(s + (size_t)off * 8 + 4);
    bf16x8 v;
    #pragma unroll
    for (int j = 0; j < 8; ++j) v[j] = bf16_bits(f[j]);
    *(bf16x8*)(d + (size_t)off * 8) = v;
}

#define KVSTRIDE 196608   // 2048*96 elements per (b,g)

// ---------------------------------------------------------------------------
// gemm1 with FUSED KV EPILOGUE (R13). m97 body + XCD swizzle unchanged
// (R6-proven). Column-blocks split exactly at Q/K/V boundaries (1536=12*128,
// 1920=15*128):
//   n0 <  1536 : Q block  -> normal store to qkv (flash ropes Q in-register)
//   n0 <  1920 : K block  -> rope in epilogue, scatter to frag-ordered Kbuf
//   else       : V block  -> scatter to frag-ordered Vtbuf
// C-layout: lane (quad,l16) holds col=..+l16, rows quad*4+r, so rope pair
// partner = lane^1 (one __shfl_xor); d parity == lane parity. Per-element
// frag addresses transcribed from the R11/R12-proven kv_prep:
//   K (n,d): bg*KVSTRIDE + ((n>>4)*3+(d>>5))<<9 + (((d>>3)&3)<<4|n&15)*8+(d&7)
//   V (n,d): bg*KVSTRIDE + ((n>>6)*12+((n&63)>>5)+(d>>4)*2)<<9
//                        + (((n>>3)&3)<<4|d&15)*8 + (n&7)
// Deletes kv_prep (12.6MB round-trip + dispatch); K/V region of qkv unwritten
// (dead: flash reads Kbuf/Vtbuf, gemm2 reads cols<1536).
// ---------------------------------------------------------------------------
__global__ __launch_bounds__(256) void gemm_qkv_fused(
    const short* __restrict__ A,
    const short* __restrict__ B,
    __hip_bfloat16* __restrict__ C,
    short* __restrict__ Kbuf,
    short* __restrict__ Vtbuf)
{
    __shared__ __align__(16) short As[128][32];
    __shared__ __align__(16) short Bs[128][32];

    const int tid  = threadIdx.x;
    const int wave = tid >> 6;
    const int lane = tid & 63;
    const int quad = lane >> 4;
    const int l16  = lane & 15;
    const int wm = (wave >> 1) * 64;
    const int wn = (wave & 1) * 64;

    // XCD swizzle: 1D grid of 576 (%8==0), bx fastest (nbx = 18)
    const int cpx = gridDim.x >> 3;
    const int swz = (blockIdx.x & 7) * cpx + (blockIdx.x >> 3);
    const int bx  = swz % 18;
    const int by  = swz / 18;
    const int m0 = by * 128;
    const int n0 = bx * 128;

    const int lrow = lane >> 2;
    const int lcol = (lane & 3) * 8;

    f32x4 acc[4][4] = {};

    for (int k0 = 0; k0 < DM; k0 += 32) {
        __syncthreads();
        #pragma unroll
        for (int i = 0; i < 2; ++i) {
            const int j = wave * 2 + i;
            gload_lds16(A + (size_t)(m0 + j * 16 + lrow) * DM + k0 + lcol, &As[j * 16][0]);
            gload_lds16(B + (size_t)(n0 + j * 16 + lrow) * DM + k0 + lcol, &Bs[j * 16][0]);
        }
        __syncthreads();

        bf16x8 af[4], bfr[4];
        #pragma unroll
        for (int i = 0; i < 4; ++i)
            af[i] = *(const bf16x8*)&As[wm + i * 16 + l16][quad * 8];
        #pragma unroll
        for (int j = 0; j < 4; ++j)
            bfr[j] = *(const bf16x8*)&Bs[wn + j * 16 + l16][quad * 8];
        #pragma unroll
        for (int i = 0; i < 4; ++i)
            #pragma unroll
            for (int j = 0; j < 4; ++j)
                acc[i][j] = __builtin_amdgcn_mfma_f32_16x16x32_bf16(
                    af[i], bfr[j], acc[i][j], 0, 0, 0);
    }

    if (n0 < 1536) {
        // ---- Q block: normal store (raw Q; flash ropes it in-register)
        #pragma unroll
        for (int i = 0; i < 4; ++i)
          #pragma unroll
          for (int j = 0; j < 4; ++j)
            #pragma unroll
            for (int r = 0; r < 4; ++r) {
                const int row = m0 + wm + i * 16 + quad * 4 + r;
                const int col = n0 + wn + j * 16 + l16;
                store_c(C + (size_t)row * QKVD + col, acc[i][j][r]);
            }
    } else if (n0 < 1920) {
        // ---- K block: rope in epilogue -> frag-ordered Kbuf
        #pragma unroll
        for (int j = 0; j < 4; ++j) {
            const int col = n0 + wn + j * 16 + l16;
            const int cg  = col - 1536;
            const int g   = cg / 96;
            const int d   = cg - g * 96;
            const int axis = d >> 5;
            const int lp   = (d & 31) >> 1;
            const float freq = exp2f(-(float)lp * 0.8304820237f);
            #pragma unroll
            for (int i = 0; i < 4; ++i)
                #pragma unroll
                for (int r = 0; r < 4; ++r) {
                    const int row = m0 + wm + i * 16 + quad * 4 + r;
                    const int n  = row & (NSEQ - 1);
                    const int bb = row >> 11;
                    const float v  = acc[i][j][r];
                    const float pv = __shfl_xor(v, 1);
                    const int pos = (axis == 0) ? (n >> 8)
                                  : (axis == 1) ? ((n >> 4) & 15) : (n & 15);
                    float sn, cs;
                    sincosf((float)pos * freq, &sn, &cs);
                    // even d: lane holds x0 -> x0*c - x1*s
                    // odd  d: lane holds x1 -> x0*s + x1*c (x0 = partner)
                    const float out = ((d & 1) == 0) ? (v * cs - pv * sn)
                                                     : (pv * sn + v * cs);
                    short* kb = Kbuf + (size_t)(bb * NG + g) * KVSTRIDE
                              + ((size_t)((n >> 4) * 3 + (d >> 5)) << 9)
                              + ((((d >> 3) & 3) << 4) + (n & 15)) * 8 + (d & 7);
                    *kb = bf16_bits(out);
                }
        }
    } else {
        // ---- V block: straight scatter -> frag-ordered Vtbuf
        #pragma unroll
        for (int j = 0; j < 4; ++j) {
            const int col = n0 + wn + j * 16 + l16;
            const int cg  = col - 1920;
            const int g   = cg / 96;
            const int d   = cg - g * 96;
            #pragma unroll
            for (int i = 0; i < 4; ++i)
                #pragma unroll
                for (int r = 0; r < 4; ++r) {
                    const int row = m0 + wm + i * 16 + quad * 4 + r;
                    const int n  = row & (NSEQ - 1);
                    const int bb = row >> 11;
                    short* vb = Vtbuf + (size_t)(bb * NG + g) * KVSTRIDE
                              + ((size_t)((n >> 6) * 12 + ((n & 63) >> 5) + (d >> 4) * 2) << 9)
                              + ((((n >> 3) & 3) << 4) + (d & 15)) * 8 + (n & 7);
                    *vb = bf16_bits(acc[i][j][r]);
                }
        }
    }
}

// ---------------------------------------------------------------------------
// Async bf16 GEMM, m97 structure + bijective XCD chunk swizzle (R6-proven).
// Used for gemm2 (and gemm1 in the fallback path).
// ---------------------------------------------------------------------------
template <typename TC>
__global__ __launch_bounds__(256) void gemm_async(
    const short* __restrict__ A,
    const short* __restrict__ B,
    TC* __restrict__ C,
    int M, int Nc, int K, int lda, int ldb, int nbx)
{
    __shared__ __align__(16) short As[128][32];
    __shared__ __align__(16) short Bs[128][32];

    const int tid  = threadIdx.x;
    const int wave = tid >> 6;
    const int lane = tid & 63;
    const int quad = lane >> 4;
    const int l16  = lane & 15;
    const int wm = (wave >> 1) * 64;
    const int wn = (wave & 1) * 64;

    const int cpx = gridDim.x >> 3;
    const int swz = (blockIdx.x & 7) * cpx + (blockIdx.x >> 3);
    const int bx  = swz % nbx;
    const int by  = swz / nbx;
    const int m0 = by * 128;
    const int n0 = bx * 128;

    const int lrow = lane >> 2;
    const int lcol = (lane & 3) * 8;

    f32x4 acc[4][4] = {};

    for (int k0 = 0; k0 < K; k0 += 32) {
        __syncthreads();
        #pragma unroll
        for (int i = 0; i < 2; ++i) {
            const int j = wave * 2 + i;
            gload_lds16(A + (size_t)(m0 + j * 16 + lrow) * lda + k0 + lcol, &As[j * 16][0]);
            gload_lds16(B + (size_t)(n0 + j * 16 + lrow) * ldb + k0 + lcol, &Bs[j * 16][0]);
        }
        __syncthreads();

        bf16x8 af[4], bfr[4];
        #pragma unroll
        for (int i = 0; i < 4; ++i)
            af[i] = *(const bf16x8*)&As[wm + i * 16 + l16][quad * 8];
        #pragma unroll
        for (int j = 0; j < 4; ++j)
            bfr[j] = *(const bf16x8*)&Bs[wn + j * 16 + l16][quad * 8];
        #pragma unroll
        for (int i = 0; i < 4; ++i)
            #pragma unroll
            for (int j = 0; j < 4; ++j)
                acc[i][j] = __builtin_amdgcn_mfma_f32_16x16x32_bf16(
                    af[i], bfr[j], acc[i][j], 0, 0, 0);
    }

    #pragma unroll
    for (int i = 0; i < 4; ++i)
      #pragma unroll
      for (int j = 0; j < 4; ++j)
        #pragma unroll
        for (int r = 0; r < 4; ++r) {
            const int row = m0 + wm + i * 16 + quad * 4 + r;
            const int col = n0 + wn + j * 16 + l16;
            store_c(C + (size_t)row * Nc + col, acc[i][j][r]);
        }
}

// ---------------------------------------------------------------------------
// LDS-tiled GEMM (m93 pattern) — gemm2 FALLBACK when ws can't hold wo_bf16.
// ---------------------------------------------------------------------------
#define KSTR 40

template <typename TA, typename TB, typename TC>
__global__ __launch_bounds__(256) void gemm_tiled(
    const TA* __restrict__ A,
    const TB* __restrict__ B,
    TC* __restrict__ C,
    int M, int Nc, int K, int lda)
{
    __shared__ __align__(16) short As[128][KSTR];
    __shared__ __align__(16) short Bs[128][KSTR];

    const int tid  = threadIdx.x;
    const int wave = tid >> 6;
    const int lane = tid & 63;
    const int quad = lane >> 4;
    const int l16  = lane & 15;
    const int wm = (wave >> 1) * 64;
    const int wn = (wave & 1) * 64;
    const int m0 = blockIdx.y * 128;
    const int n0 = blockIdx.x * 128;

    const int srow  = tid >> 1;
    const int skseg = (tid & 1) << 4;
    const TA* Asrc = A + (size_t)(m0 + srow) * lda + skseg;
    const TB* Bsrc = B + (size_t)(n0 + srow) * K + skseg;

    f32x4 acc[4][4] = {};

    for (int k0 = 0; k0 < K; k0 += 32) {
        __syncthreads();
        stage16(&As[srow][skseg], Asrc + k0);
        stage16(&Bs[srow][skseg], Bsrc + k0);
        __syncthreads();

        bf16x8 af[4], bfr[4];
        #pragma unroll
        for (int i = 0; i < 4; ++i)
            af[i] = *(const bf16x8*)&As[wm + i * 16 + l16][quad * 8];
        #pragma unroll
        for (int j = 0; j < 4; ++j)
            bfr[j] = *(const bf16x8*)&Bs[wn + j * 16 + l16][quad * 8];
        #pragma unroll
        for (int i = 0; i < 4; ++i)
            #pragma unroll
            for (int j = 0; j < 4; ++j)
                acc[i][j] = __builtin_amdgcn_mfma_f32_16x16x32_bf16(
                    af[i], bfr[j], acc[i][j], 0, 0, 0);
    }

    #pragma unroll
    for (int i = 0; i < 4; ++i)
      #pragma unroll
      for (int j = 0; j < 4; ++j)
        #pragma unroll
        for (int r = 0; r < 4; ++r) {
            const int row = m0 + wm + i * 16 + quad * 4 + r;
            const int col = n0 + wn + j * 16 + l16;
            store_c(C + (size_t)row * Nc + col, acc[i][j][r]);
        }
}

// ---------------------------------------------------------------------------
// KV prep (R12, fallback path only): K roped into frag Kbuf + V copied into
// frag Vtbuf from the qkv K/V region.
// ---------------------------------------------------------------------------
__global__ __launch_bounds__(256) void kv_prep(
    const __hip_bfloat16* __restrict__ qkv,
    short* __restrict__ Kbuf,
    short* __restrict__ Vtbuf)
{
    const int e    = blockIdx.x * 256 + threadIdx.x;
    const int p2   = e % 48;
    const int t2   = e / 48;
    const int slot = t2 & 7;
    const int r    = t2 >> 3;
    const int n    = r & (NSEQ - 1);
    const int b    = r >> 11;

    const int axis = p2 >> 4;
    const int lp   = p2 & 15;
    const int d0   = axis * 32 + 2 * lp;

    if (slot >= 4) {
        const int g  = slot - 4;
        const int bg = b * NG + g;
        const short* p = (const short*)(qkv + (size_t)r * QKVD + DM + NG * HD + g * HD + d0);
        const short v0 = p[0];
        const short v1 = p[1];
        short* vb = Vtbuf + (size_t)bg * KVSTRIDE;
        const int tbase = (n >> 6) * 12 + ((n & 63) >> 5);
        const int qoff  = ((n >> 3) & 3) << 4;
        const int eidx  = n & 7;
        vb[((size_t)(tbase + (d0 >> 4) * 2) << 9) + (qoff + (d0 & 15)) * 8 + eidx] = v0;
        vb[((size_t)(tbase + ((d0 + 1) >> 4) * 2) << 9) + (qoff + ((d0 + 1) & 15)) * 8 + eidx] = v1;
        return;
    }

    const int pt = n >> 8;
    const int ph = (n >> 4) & 15;
    const int pw = n & 15;
    const int pos  = (axis == 0) ? pt : ((axis == 1) ? ph : pw);
    const float freq = exp2f(-(float)lp * 0.8304820237f);
    float s, c;
    sincosf((float)pos * freq, &s, &c);

    const int g  = slot;
    const int bg = b * NG + g;
    const __hip_bfloat16* p = qkv + (size_t)r * QKVD + DM + g * HD + d0;
    const float x0 = __bfloat162float(p[0]);
    const float x1 = __bfloat162float(p[1]);
    short* kb = Kbuf + (size_t)bg * KVSTRIDE
              + ((size_t)((n >> 4) * 3 + (d0 >> 5)) << 9)
              + ((((d0 >> 3) & 3) << 4) + (n & 15)) * 8 + (d0 & 7);
    kb[0] = bf16_bits(x0 * c - x1 * s);
    kb[1] = bf16_bits(x0 * s + x1 * c);
}

// ---------------------------------------------------------------------------
// MFMA flash attention — R12 body EXACTLY (in-register Q-rope + R9 main
// loop; 100us proven, 44 VGPR).
// LDS: KsLin 12.3K + VtLin 12.3K + Pw[8][16][72] 18.4K = 43008 B.
// ---------------------------------------------------------------------------
#define QT 128
#define KC 64
#define PSTR 72

__global__ __launch_bounds__(512) void flash_attn(
    __hip_bfloat16* __restrict__ qkv,
    const short* __restrict__ Kbuf,
    const short* __restrict__ Vtbuf)
{
    __shared__ __align__(16) short KsLin[6144];
    __shared__ __align__(16) short VtLin[6144];
    __shared__ __align__(16) short Pw[8][16][PSTR];

    const int tid  = threadIdx.x;
    const int wave = tid >> 6;
    const int lane = tid & 63;
    const int quad = lane >> 4;
    const int l16  = lane & 15;

    const int id  = blockIdx.x;
    const int bg  = id & 7;
    const int k   = id >> 3;
    const int b   = bg >> 2, g = bg & 3;
    const int h   = g * 4 + (k & 3);
    const int n0  = (k >> 2) * QT;

    const short* Kc = Kbuf  + (size_t)bg * KVSTRIDE;
    const short* Vc = Vtbuf + (size_t)bg * KVSTRIDE;
    const int lane8 = lane * 8;

    // ---- Q fragments, roped IN REGISTERS (raw Q from gemm1 output).
    const int nrow = n0 + wave * 16 + l16;
    const __hip_bfloat16* Qb = qkv + (size_t)(b * NSEQ + nrow) * QKVD + h * HD;
    const float posv[3] = { (float)(nrow >> 8), (float)((nrow >> 4) & 15), (float)(nrow & 15) };
    bf16x8 qa[3];
    #pragma unroll
    for (int kk = 0; kk < 3; ++kk) {
        bf16x8 q = *(const bf16x8*)(Qb + kk * 32 + quad * 8);
        #pragma unroll
        for (int i = 0; i < 4; ++i) {
            const int lp = quad * 4 + i;
            const float freq = exp2f(-(float)lp * 0.8304820237f);
            float s, c;
            sincosf(posv[kk] * freq, &s, &c);
            const float x0 = bf16_val(q[2 * i]);
            const float x1 = bf16_val(q[2 * i + 1]);
            q[2 * i]     = bf16_bits(x0 * c - x1 * s);
            q[2 * i + 1] = bf16_bits(x0 * s + x1 * c);
        }
        qa[kk] = q;
    }

    f32x4 o[6] = {};
    float psum[4] = {0.f, 0.f, 0.f, 0.f};
    const float c1 = 0.14724434f;
    const float c2 = -5.7707802f;
    const int sw = l16 >> 2;

    for (int j0 = 0; j0 < NSEQ; j0 += KC) {
        __syncthreads();
        {
            const short* Kch = Kc + ((size_t)((j0 >> 4) * 3) << 9);
            const short* Vch = Vc + ((size_t)((j0 >> 6) * 12) << 9);
            const short* sb = (wave < 4) ? Kch : Vch;
            short* db       = (wave < 4) ? KsLin : VtLin;
            #pragma unroll
            for (int i = 0; i < 3; ++i) {
                const int t = (wave & 3) * 3 + i;
                gload_lds16(sb + ((size_t)t << 9) + lane8, db + (t << 9));
            }
        }
        __syncthreads();

        f32x4 S[4] = {};
        #pragma unroll
        for (int nt = 0; nt < 4; ++nt) {
            bf16x8 kf[3];
            #pragma unroll
            for (int kk = 0; kk < 3; ++kk)
                kf[kk] = *(const bf16x8*)&KsLin[((nt * 3 + kk) << 9) + lane8];
            #pragma unroll
            for (int kk = 0; kk < 3; ++kk)
                S[nt] = __builtin_amdgcn_mfma_f32_16x16x32_bf16(qa[kk], kf[kk], S[nt], 0, 0, 0);
        }

        #pragma unroll
        for (int nt = 0; nt < 4; ++nt) {
            const int cb   = nt * 2 + (l16 >> 3);
            const int colp = ((cb ^ quad) << 3) + (l16 & 7);
            #pragma unroll
            for (int r = 0; r < 4; ++r) {
                const float p = exp2f(fmaf(S[nt][r], c1, c2));
                psum[r] += p;
                Pw[wave][quad * 4 + r][colp] = bf16_bits(p);
            }
        }

        bf16x8 pa0 = *(const bf16x8*)&Pw[wave][l16][(quad ^ sw) << 3];
        bf16x8 pa1 = *(const bf16x8*)&Pw[wave][l16][((quad ^ sw) + 4) << 3];
        #pragma unroll
        for (int dt = 0; dt < 6; ++dt) {
            bf16x8 vb0 = *(const bf16x8*)&VtLin[((dt * 2 + 0) << 9) + lane8];
            bf16x8 vb1 = *(const bf16x8*)&VtLin[((dt * 2 + 1) << 9) + lane8];
            o[dt] = __builtin_amdgcn_mfma_f32_16x16x32_bf16(pa0, vb0, o[dt], 0, 0, 0);
            o[dt] = __builtin_amdgcn_mfma_f32_16x16x32_bf16(pa1, vb1, o[dt], 0, 0, 0);
        }
    }

    #pragma unroll
    for (int off = 1; off < 16; off <<= 1)
        #pragma unroll
        for (int r = 0; r < 4; ++r)
            psum[r] += __shfl_xor(psum[r], off);
    float inv_l[4];
    #pragma unroll
    for (int r = 0; r < 4; ++r) inv_l[r] = 1.f / psum[r];

    #pragma unroll
    for (int dt = 0; dt < 6; ++dt)
        #pragma unroll
        for (int r = 0; r < 4; ++r) {
            __hip_bfloat16* op =
                qkv + (size_t)(b * NSEQ + n0 + wave * 16 + quad * 4 + r) * QKVD
                    + h * HD + dt * 16 + l16;
            *op = __float2bfloat16(o[dt][r] * inv_l[r]);
        }
}

// ---------------------------------------------------------------------------
// Memory plan (fused path, ws_size >= 29,884,416):
//   ws:    qkv [0, 18.87MB) | wob [18.87, 23.59MB) | Kbuf/Vtbuf [23.59, 29.88MB)
//   d_out: xb [0, 12.58MB) | wqb [12.58, 19.66MB)  (both dead after gemm1)
//   gemm1 epilogue writes K/V straight to ws KV buffers; kv_prep deleted.
// Fallback (smaller ws): exact R12 path (KV in d_out, kv_prep kernel).
// ---------------------------------------------------------------------------
extern "C" void kernel_launch(void* const* d_in, const int* in_sizes, int n_in,
                              void* d_out, int out_size, void* d_ws, size_t ws_size,
                              hipStream_t stream)
{
    const float* x    = (const float*)d_in[0];
    const float* wqkv = (const float*)d_in[1];
    const float* wo   = (const float*)d_in[2];

    __hip_bfloat16* qkv = (__hip_bfloat16*)d_ws;
    short* xb    = (short*)d_out;                          // 12,582,912 B
    short* wqb   = (short*)((char*)d_out + 12582912);      //  7,077,888 B

    const bool wo_in_ws = ws_size >= 23592960;
    const bool fuse_kv  = ws_size >= 29884416;
    short* wob = wo_in_ws ? (short*)((char*)d_ws + 18874368) : (short*)d_out;

    short* Kbuf  = fuse_kv ? (short*)((char*)d_ws + 23592960) : (short*)d_out;
    short* Vtbuf = fuse_kv ? (short*)((char*)d_ws + 26738688)
                           : (short*)((char*)d_out + 3145728);

    // fp32 -> bf16 converts
    cvt3_bf16<<<wo_in_ws ? 5952 : 4800, 256, 0, stream>>>(x, xb, wqkv, wqb, wo, wob);

    if (fuse_kv) {
        // GEMM1 with fused rope-K/V scatter epilogue (no kv_prep)
        gemm_qkv_fused<<<(QKVD / 128) * (MROWS / 128), 256, 0, stream>>>(
            xb, wqb, qkv, Kbuf, Vtbuf);
    } else {
        gemm_async<__hip_bfloat16>
            <<<(QKVD / 128) * (MROWS / 128), 256, 0, stream>>>(
                xb, wqb, qkv, MROWS, QKVD, DM, DM, DM, QKVD / 128);
        kv_prep<<<(MROWS * 8 * 48) / 256, 256, 0, stream>>>(qkv, Kbuf, Vtbuf);
    }

    // 512 blocks x 512 threads: 16 q-blocks of 128 rows x 32 (b,h)
    flash_attn<<<dim3(NSEQ / QT * BB * NH, 1), 512, 0, stream>>>(qkv, Kbuf, Vtbuf);

    // GEMM2: out = attn @ w_o^T
    if (wo_in_ws) {
        gemm_async<float>
            <<<(DM / 128) * (MROWS / 128), 256, 0, stream>>>(
                (const short*)qkv, wob, (float*)d_out, MROWS, DM, DM, QKVD, DM, DM / 128);
    } else {
        gemm_tiled<__hip_bfloat16, float, float>
            <<<dim3(DM / 128, MROWS / 128), 256, 0, stream>>>(
                qkv, wo, (float*)d_out, MROWS, DM, DM, QKVD);
    }
}

// Round 14
// 274.043 us; speedup vs baseline: 2.8654x; 2.8654x over previous
//
#include <hip/hip_runtime.h>
#include <hip/hip_bf16.h>

typedef short bf16x8 __attribute__((ext_vector_type(8)));
typedef float f32x4  __attribute__((ext_vector_type(4)));

#define NH    16
#define NG    4
#define HD    96
#define DM    1536
#define BB    2
#define NSEQ  2048
#define QKVD  2304
#define MROWS (BB * NSEQ)   // 4096
// grid dims fixed by setup_inputs: 8 x 16 x 16 (t,h,w), N = 2048

__device__ __forceinline__ short bf16_bits(float v)
{
    __hip_bfloat16 h = __float2bfloat16(v);
    return *reinterpret_cast<short*>(&h);
}

__device__ __forceinline__ float bf16_val(short v)
{
    __hip_bfloat16 h = *reinterpret_cast<__hip_bfloat16*>(&v);
    return __bfloat162float(h);
}

// ---- staging: 16 contiguous elements -> 16 bf16 shorts in LDS -------------
__device__ __forceinline__ void stage16(short* dst, const float* src)
{
    float f[16];
    *(float4*)(f + 0)  = *(const float4*)(src + 0);
    *(float4*)(f + 4)  = *(const float4*)(src + 4);
    *(float4*)(f + 8)  = *(const float4*)(src + 8);
    *(float4*)(f + 12) = *(const float4*)(src + 12);
    bf16x8 v0, v1;
    #pragma unroll
    for (int j = 0; j < 8; ++j) { v0[j] = bf16_bits(f[j]); v1[j] = bf16_bits(f[8 + j]); }
    *(bf16x8*)dst = v0;
    *(bf16x8*)(dst + 8) = v1;
}
__device__ __forceinline__ void stage16(short* dst, const __hip_bfloat16* src)
{
    *(bf16x8*)dst       = *(const bf16x8*)src;
    *(bf16x8*)(dst + 8) = *(const bf16x8*)(src + 8);
}

__device__ __forceinline__ void store_c(__hip_bfloat16* p, float v)
{
    *p = __float2bfloat16(v);
}
__device__ __forceinline__ void store_c(float* p, float v) { *p = v; }

// ---- async global->LDS, 16B per lane (m97 pattern) ------------------------
__device__ __forceinline__ void gload_lds16(const short* g, short* lds)
{
    __builtin_amdgcn_global_load_lds(
        (const __attribute__((address_space(1))) unsigned int*)g,
        (__attribute__((address_space(3))) unsigned int*)lds,
        16, 0, 0);
}

// ---------------------------------------------------------------------------
// fp32 -> bf16 bulk convert (one pass): x (786432 u8), w_qkv (442368 u8),
// w_o (294912 u8, only if workspace fits). 8 elems / thread, fully coalesced.
// ---------------------------------------------------------------------------
__global__ __launch_bounds__(256) void cvt3_bf16(
    const float* __restrict__ x,  short* __restrict__ xb,
    const float* __restrict__ wq, short* __restrict__ wqb,
    const float* __restrict__ wo, short* __restrict__ wob)
{
    const int i = blockIdx.x * 256 + threadIdx.x;
    const float* s; short* d; int off;
    if (i < 786432)       { s = x;  d = xb;  off = i; }
    else if (i < 1228800) { s = wq; d = wqb; off = i - 786432; }
    else                  { s = wo; d = wob; off = i - 1228800; }
    float f[8];
    *(float4*)(f + 0) = *(const float4*)(s + (size_t)off * 8);
    *(float4*)(f + 4) = *(const float4*)(s + (size_t)off * 8 + 4);
    bf16x8 v;
    #pragma unroll
    for (int j = 0; j < 8; ++j) v[j] = bf16_bits(f[j]);
    *(bf16x8*)(d + (size_t)off * 8) = v;
}

// ---------------------------------------------------------------------------
// Async bf16 GEMM, m97 structure + bijective XCD chunk swizzle (R6-proven).
// ---------------------------------------------------------------------------
template <typename TC>
__global__ __launch_bounds__(256) void gemm_async(
    const short* __restrict__ A,
    const short* __restrict__ B,
    TC* __restrict__ C,
    int M, int Nc, int K, int lda, int ldb, int nbx)
{
    __shared__ __align__(16) short As[128][32];
    __shared__ __align__(16) short Bs[128][32];

    const int tid  = threadIdx.x;
    const int wave = tid >> 6;
    const int lane = tid & 63;
    const int quad = lane >> 4;
    const int l16  = lane & 15;
    const int wm = (wave >> 1) * 64;
    const int wn = (wave & 1) * 64;

    // XCD swizzle: grid is 1D, gridDim.x % 8 == 0
    const int cpx = gridDim.x >> 3;
    const int swz = (blockIdx.x & 7) * cpx + (blockIdx.x >> 3);
    const int bx  = swz % nbx;
    const int by  = swz / nbx;
    const int m0 = by * 128;
    const int n0 = bx * 128;

    const int lrow = lane >> 2;        // 16 rows per 1024B wave-load
    const int lcol = (lane & 3) * 8;   // 4 x 16B segments per row

    f32x4 acc[4][4] = {};

    for (int k0 = 0; k0 < K; k0 += 32) {
        __syncthreads();               // previous tile fully consumed
        #pragma unroll
        for (int i = 0; i < 2; ++i) {
            const int j = wave * 2 + i;        // 8 loads cover 128 rows
            gload_lds16(A + (size_t)(m0 + j * 16 + lrow) * lda + k0 + lcol, &As[j * 16][0]);
            gload_lds16(B + (size_t)(n0 + j * 16 + lrow) * ldb + k0 + lcol, &Bs[j * 16][0]);
        }
        __syncthreads();               // drains vmcnt (compiler-inserted)

        bf16x8 af[4], bfr[4];
        #pragma unroll
        for (int i = 0; i < 4; ++i)
            af[i] = *(const bf16x8*)&As[wm + i * 16 + l16][quad * 8];
        #pragma unroll
        for (int j = 0; j < 4; ++j)
            bfr[j] = *(const bf16x8*)&Bs[wn + j * 16 + l16][quad * 8];
        #pragma unroll
        for (int i = 0; i < 4; ++i)
            #pragma unroll
            for (int j = 0; j < 4; ++j)
                acc[i][j] = __builtin_amdgcn_mfma_f32_16x16x32_bf16(
                    af[i], bfr[j], acc[i][j], 0, 0, 0);
    }

    #pragma unroll
    for (int i = 0; i < 4; ++i)
      #pragma unroll
      for (int j = 0; j < 4; ++j)
        #pragma unroll
        for (int r = 0; r < 4; ++r) {
            const int row = m0 + wm + i * 16 + quad * 4 + r;
            const int col = n0 + wn + j * 16 + l16;
            store_c(C + (size_t)row * Nc + col, acc[i][j][r]);
        }
}

// ---------------------------------------------------------------------------
// LDS-tiled GEMM (m93 pattern) — gemm2 FALLBACK when ws can't hold wo_bf16.
// ---------------------------------------------------------------------------
#define KSTR 40

template <typename TA, typename TB, typename TC>
__global__ __launch_bounds__(256) void gemm_tiled(
    const TA* __restrict__ A,
    const TB* __restrict__ B,
    TC* __restrict__ C,
    int M, int Nc, int K, int lda)
{
    __shared__ __align__(16) short As[128][KSTR];
    __shared__ __align__(16) short Bs[128][KSTR];

    const int tid  = threadIdx.x;
    const int wave = tid >> 6;
    const int lane = tid & 63;
    const int quad = lane >> 4;
    const int l16  = lane & 15;
    const int wm = (wave >> 1) * 64;
    const int wn = (wave & 1) * 64;
    const int m0 = blockIdx.y * 128;
    const int n0 = blockIdx.x * 128;

    const int srow  = tid >> 1;
    const int skseg = (tid & 1) << 4;
    const TA* Asrc = A + (size_t)(m0 + srow) * lda + skseg;
    const TB* Bsrc = B + (size_t)(n0 + srow) * K + skseg;

    f32x4 acc[4][4] = {};

    for (int k0 = 0; k0 < K; k0 += 32) {
        __syncthreads();
        stage16(&As[srow][skseg], Asrc + k0);
        stage16(&Bs[srow][skseg], Bsrc + k0);
        __syncthreads();

        bf16x8 af[4], bfr[4];
        #pragma unroll
        for (int i = 0; i < 4; ++i)
            af[i] = *(const bf16x8*)&As[wm + i * 16 + l16][quad * 8];
        #pragma unroll
        for (int j = 0; j < 4; ++j)
            bfr[j] = *(const bf16x8*)&Bs[wn + j * 16 + l16][quad * 8];
        #pragma unroll
        for (int i = 0; i < 4; ++i)
            #pragma unroll
            for (int j = 0; j < 4; ++j)
                acc[i][j] = __builtin_amdgcn_mfma_f32_16x16x32_bf16(
                    af[i], bfr[j], acc[i][j], 0, 0, 0);
    }

    #pragma unroll
    for (int i = 0; i < 4; ++i)
      #pragma unroll
      for (int j = 0; j < 4; ++j)
        #pragma unroll
        for (int r = 0; r < 4; ++r) {
            const int row = m0 + wm + i * 16 + quad * 4 + r;
            const int col = n0 + wn + j * 16 + l16;
            store_c(C + (size_t)row * Nc + col, acc[i][j][r]);
        }
}

// ---------------------------------------------------------------------------
// KV prep (R12): K roped directly into fragment-ordered Kbuf + V copied into
// fragment-ordered Vtbuf. Adjacent threads write adjacent bytes (d0 is
// thread-fastest) -> full store coalescing (R13's epilogue-scatter lesson).
// Grid: MROWS*8*48/256 = 6144 blocks.
//   K elem (n,d): tile (n>>4)*3 + (d>>5); off (((d>>3)&3)<<4 | n&15)*8 + (d&7)
//   V elem (n,d): tile (n>>6)*12 + (d>>4)*2 + ((n&63)>>5);
//                 off  (((n>>3)&3)<<4 | d&15)*8 + (n&7)
// ---------------------------------------------------------------------------
#define KVSTRIDE 196608   // 2048*96 elements per (b,g)

__global__ __launch_bounds__(256) void kv_prep(
    const __hip_bfloat16* __restrict__ qkv,
    short* __restrict__ Kbuf,
    short* __restrict__ Vtbuf)
{
    const int e    = blockIdx.x * 256 + threadIdx.x;
    const int p2   = e % 48;
    const int t2   = e / 48;
    const int slot = t2 & 7;
    const int r    = t2 >> 3;          // 0..4095
    const int n    = r & (NSEQ - 1);
    const int b    = r >> 11;

    const int axis = p2 >> 4;
    const int lp   = p2 & 15;
    const int d0   = axis * 32 + 2 * lp;

    if (slot >= 4) {
        // ---- V: straight copy into Vtbuf fragment layout (no rotation)
        const int g  = slot - 4;
        const int bg = b * NG + g;
        const short* p = (const short*)(qkv + (size_t)r * QKVD + DM + NG * HD + g * HD + d0);
        const short v0 = p[0];
        const short v1 = p[1];
        short* vb = Vtbuf + (size_t)bg * KVSTRIDE;
        const int tbase = (n >> 6) * 12 + ((n & 63) >> 5);
        const int qoff  = ((n >> 3) & 3) << 4;
        const int eidx  = n & 7;
        vb[((size_t)(tbase + (d0 >> 4) * 2) << 9) + (qoff + (d0 & 15)) * 8 + eidx] = v0;
        vb[((size_t)(tbase + ((d0 + 1) >> 4) * 2) << 9) + (qoff + ((d0 + 1) & 15)) * 8 + eidx] = v1;
        return;
    }

    // ---- K: rope -> Kbuf fragment layout (no qkv writeback)
    const int pt = n >> 8;
    const int ph = (n >> 4) & 15;
    const int pw = n & 15;
    const int pos  = (axis == 0) ? pt : ((axis == 1) ? ph : pw);
    const float freq = exp2f(-(float)lp * 0.8304820237f);
    float s, c;
    sincosf((float)pos * freq, &s, &c);

    const int g  = slot;
    const int bg = b * NG + g;
    const __hip_bfloat16* p = qkv + (size_t)r * QKVD + DM + g * HD + d0;
    const float x0 = __bfloat162float(p[0]);
    const float x1 = __bfloat162float(p[1]);
    short* kb = Kbuf + (size_t)bg * KVSTRIDE
              + ((size_t)((n >> 4) * 3 + (d0 >> 5)) << 9)
              + ((((d0 >> 3) & 3) << 4) + (n & 15)) * 8 + (d0 & 7);
    kb[0] = bf16_bits(x0 * c - x1 * s);
    kb[1] = bf16_bits(x0 * s + x1 * c);
}

// ---------------------------------------------------------------------------
// MFMA flash attention — R12 body EXACTLY (proven 275.4us total config):
// R9 main loop (frag-linear LDS staging via global_load_lds, QT=128, 8 waves,
// 2 barriers/chunk, XCD-swizzled 1D grid, Pw col-swizzle, 44 VGPR) +
// IN-REGISTER Q-ROPE prologue (Q fragment holds 4 complete lane-local
// rotation pairs; 12 sincosf once per block).
// LDS: KsLin 12.3K + VtLin 12.3K + Pw[8][16][72] 18.4K = 43008 B.
// ---------------------------------------------------------------------------
#define QT 128
#define KC 64
#define PSTR 72

__global__ __launch_bounds__(512) void flash_attn(
    __hip_bfloat16* __restrict__ qkv,
    const short* __restrict__ Kbuf,
    const short* __restrict__ Vtbuf)
{
    __shared__ __align__(16) short KsLin[6144];      // 12 frag tiles x 512 shorts
    __shared__ __align__(16) short VtLin[6144];      // 12 frag tiles x 512 shorts
    __shared__ __align__(16) short Pw[8][16][PSTR];  // per-wave P (col-swizzled)

    const int tid  = threadIdx.x;
    const int wave = tid >> 6;          // 0..7
    const int lane = tid & 63;
    const int quad = lane >> 4;
    const int l16  = lane & 15;

    // XCD-aware decomposition: 512 blocks (%8==0), id&7 -> (b,g).
    const int id  = blockIdx.x;
    const int bg  = id & 7;
    const int k   = id >> 3;            // 0..63
    const int b   = bg >> 2, g = bg & 3;
    const int h   = g * 4 + (k & 3);
    const int n0  = (k >> 2) * QT;      // 16 q-blocks of 128 rows

    const short* Kc = Kbuf  + (size_t)bg * KVSTRIDE;
    const short* Vc = Vtbuf + (size_t)bg * KVSTRIDE;
    const int lane8 = lane * 8;

    // ---- Q fragments, roped IN REGISTERS (raw Q from gemm1 output).
    // Lane holds Q[nrow][kk*32 + quad*8 + e], e=0..7: axis=kk, pairs
    // (2i,2i+1) have lp = quad*4+i; pos from nrow's (t,h,w) decomposition.
    const int nrow = n0 + wave * 16 + l16;
    const __hip_bfloat16* Qb = qkv + (size_t)(b * NSEQ + nrow) * QKVD + h * HD;
    const float posv[3] = { (float)(nrow >> 8), (float)((nrow >> 4) & 15), (float)(nrow & 15) };
    bf16x8 qa[3];
    #pragma unroll
    for (int kk = 0; kk < 3; ++kk) {
        bf16x8 q = *(const bf16x8*)(Qb + kk * 32 + quad * 8);
        #pragma unroll
        for (int i = 0; i < 4; ++i) {
            const int lp = quad * 4 + i;
            const float freq = exp2f(-(float)lp * 0.8304820237f);
            float s, c;
            sincosf(posv[kk] * freq, &s, &c);
            const float x0 = bf16_val(q[2 * i]);
            const float x1 = bf16_val(q[2 * i + 1]);
            q[2 * i]     = bf16_bits(x0 * c - x1 * s);
            q[2 * i + 1] = bf16_bits(x0 * s + x1 * c);
        }
        qa[kk] = q;
    }

    f32x4 o[6] = {};                 // O tiles over d (C-layout rows=quad*4+r)
    float psum[4] = {0.f, 0.f, 0.f, 0.f};
    const float c1 = 0.14724434f;    // scale * log2(e)
    const float c2 = -5.7707802f;    // -4 * log2(e)
    const int sw = l16 >> 2;         // read-side Pw swizzle key ((row>>2)&3)

    for (int j0 = 0; j0 < NSEQ; j0 += KC) {
        __syncthreads();             // previous chunk fully consumed
        // ---- stage 24 frag tiles (12 K + 12 V) via async DMA, 3 per wave.
        // waves 0-3 -> K tiles 0..11; waves 4-7 -> V tiles 0..11.
        {
            const short* Kch = Kc + ((size_t)((j0 >> 4) * 3) << 9);
            const short* Vch = Vc + ((size_t)((j0 >> 6) * 12) << 9);
            const short* sb = (wave < 4) ? Kch : Vch;
            short* db       = (wave < 4) ? KsLin : VtLin;
            #pragma unroll
            for (int i = 0; i < 3; ++i) {
                const int t = (wave & 3) * 3 + i;
                gload_lds16(sb + ((size_t)t << 9) + lane8, db + (t << 9));
            }
        }
        __syncthreads();             // drains vmcnt (compiler-inserted)

        // ---- QK^T: S[nt] = Q(16x96) . K_chunk(16x96)^T, kf = lane-linear
        f32x4 S[4] = {};
        #pragma unroll
        for (int nt = 0; nt < 4; ++nt) {
            bf16x8 kf[3];
            #pragma unroll
            for (int kk = 0; kk < 3; ++kk)
                kf[kk] = *(const bf16x8*)&KsLin[((nt * 3 + kk) << 9) + lane8];
            #pragma unroll
            for (int kk = 0; kk < 3; ++kk)
                S[nt] = __builtin_amdgcn_mfma_f32_16x16x32_bf16(qa[kk], kf[kk], S[nt], 0, 0, 0);
        }

        // ---- fixed-shift softmax numerator + linear row-sum accumulation
        // write col (nt*16+l16) into swizzled 8-short block ((col>>3) ^ quad)
        #pragma unroll
        for (int nt = 0; nt < 4; ++nt) {
            const int cb   = nt * 2 + (l16 >> 3);
            const int colp = ((cb ^ quad) << 3) + (l16 & 7);
            #pragma unroll
            for (int r = 0; r < 4; ++r) {
                const float p = exp2f(fmaf(S[nt][r], c1, c2));
                psum[r] += p;
                Pw[wave][quad * 4 + r][colp] = bf16_bits(p);
            }
        }
        // no barrier: Pw[wave] is wave-private; same-wave DS ops are ordered

        // ---- PV: O += P(16x64) . V_chunk(64x96), vb = lane-linear
        bf16x8 pa0 = *(const bf16x8*)&Pw[wave][l16][(quad ^ sw) << 3];
        bf16x8 pa1 = *(const bf16x8*)&Pw[wave][l16][((quad ^ sw) + 4) << 3];
        #pragma unroll
        for (int dt = 0; dt < 6; ++dt) {
            bf16x8 vb0 = *(const bf16x8*)&VtLin[((dt * 2 + 0) << 9) + lane8];
            bf16x8 vb1 = *(const bf16x8*)&VtLin[((dt * 2 + 1) << 9) + lane8];
            o[dt] = __builtin_amdgcn_mfma_f32_16x16x32_bf16(pa0, vb0, o[dt], 0, 0, 0);
            o[dt] = __builtin_amdgcn_mfma_f32_16x16x32_bf16(pa1, vb1, o[dt], 0, 0, 0);
        }
    }

    // ---- one-time cross-lane row-sum reduction (over l16) + normalize
    #pragma unroll
    for (int off = 1; off < 16; off <<= 1)
        #pragma unroll
        for (int r = 0; r < 4; ++r)
            psum[r] += __shfl_xor(psum[r], off);
    float inv_l[4];
    #pragma unroll
    for (int r = 0; r < 4; ++r) inv_l[r] = 1.f / psum[r];

    #pragma unroll
    for (int dt = 0; dt < 6; ++dt)
        #pragma unroll
        for (int r = 0; r < 4; ++r) {
            __hip_bfloat16* op =
                qkv + (size_t)(b * NSEQ + n0 + wave * 16 + quad * 4 + r) * QKVD
                    + h * HD + dt * 16 + l16;
            *op = __float2bfloat16(o[dt][r] * inv_l[r]);
        }
}

// ---------------------------------------------------------------------------
// Memory plan (R12 checkpoint):
//   d_out (25.2MB fp32 final output), timeline-shared scratch:
//     phase 1 (cvt+gemm1):  x_bf16 [0, 12.58MB), wqkv_bf16 [12.58, 19.66MB)
//     phase 2 (kv_prep..):  Kbuf [0, 3.1MB), Vtbuf [3.1, 6.3MB)
//     phase 3 (gemm2):      final fp32 output everywhere
//   ws: qkv bf16 = 18,874,368 B; wo_bf16 appended at +18.9MB if it fits.
// ---------------------------------------------------------------------------
extern "C" void kernel_launch(void* const* d_in, const int* in_sizes, int n_in,
                              void* d_out, int out_size, void* d_ws, size_t ws_size,
                              hipStream_t stream)
{
    const float* x    = (const float*)d_in[0];
    const float* wqkv = (const float*)d_in[1];
    const float* wo   = (const float*)d_in[2];

    __hip_bfloat16* qkv = (__hip_bfloat16*)d_ws;
    short* xb    = (short*)d_out;                          // 12,582,912 B
    short* wqb   = (short*)((char*)d_out + 12582912);      //  7,077,888 B
    short* Kbuf  = (short*)d_out;
    short* Vtbuf = (short*)((char*)d_out + 3145728);

    const bool wo_in_ws = ws_size >= 23592960;
    short* wob = wo_in_ws ? (short*)((char*)d_ws + 18874368) : (short*)d_out;

    // fp32 -> bf16 converts (x + w_qkv always; w_o only when it fits in ws)
    cvt3_bf16<<<wo_in_ws ? 5952 : 4800, 256, 0, stream>>>(x, xb, wqkv, wqb, wo, wob);

    // GEMM1: qkv = x @ w_qkv^T  (async bf16 m97 structure, XCD-swizzled)
    gemm_async<__hip_bfloat16>
        <<<(QKVD / 128) * (MROWS / 128), 256, 0, stream>>>(
            xb, wqb, qkv, MROWS, QKVD, DM, DM, DM, QKVD / 128);

    // K roped -> Kbuf, V copied -> Vtbuf (Q roped in-register inside flash)
    kv_prep<<<(MROWS * 8 * 48) / 256, 256, 0, stream>>>(qkv, Kbuf, Vtbuf);

    // 512 blocks x 512 threads: 16 q-blocks of 128 rows x 32 (b,h)
    flash_attn<<<dim3(NSEQ / QT * BB * NH, 1), 512, 0, stream>>>(qkv, Kbuf, Vtbuf);

    // GEMM2: out = attn @ w_o^T
    if (wo_in_ws) {
        gemm_async<float>
            <<<(DM / 128) * (MROWS / 128), 256, 0, stream>>>(
                (const short*)qkv, wob, (float*)d_out, MROWS, DM, DM, QKVD, DM, DM / 128);
    } else {
        gemm_tiled<__hip_bfloat16, float, float>
            <<<dim3(DM / 128, MROWS / 128), 256, 0, stream>>>(
                qkv, wo, (float*)d_out, MROWS, DM, DM, QKVD);
    }
}